// Round 1
// baseline (323.206 us; speedup 1.0000x reference)
//
#include <hip/hip_runtime.h>
#include <hip/hip_bf16.h>

// Problem constants
#define BB 4
#define SS 4096
#define DM 1024
#define HH 16
#define PP 32
#define RR 8
#define DD 64
#define NTOK (BB*SS)          // 16384 tokens
#define MM NTOK               // GEMM M
#define NN DM                 // GEMM N
#define KK DM                 // GEMM K

typedef __attribute__((ext_vector_type(8))) short short8;
typedef __attribute__((ext_vector_type(4))) float floatx4;

static __device__ inline short f2bf(float f) {
    union { __hip_bfloat16 b; short s; } u; u.b = __float2bfloat16(f); return u.s;
}
static __device__ inline short8 pack8(float4 lo, float4 hi) {
    short8 r;
    r[0] = f2bf(lo.x); r[1] = f2bf(lo.y); r[2] = f2bf(lo.z); r[3] = f2bf(lo.w);
    r[4] = f2bf(hi.x); r[5] = f2bf(hi.y); r[6] = f2bf(hi.z); r[7] = f2bf(hi.w);
    return r;
}

// Fast RNE bf16 pack: identical bits to __float2bfloat16 for finite inputs.
static __device__ inline unsigned bfr(float f) {
    unsigned u = __float_as_uint(f);
    return u + 0x7fffu + ((u >> 16) & 1u);
}
static __device__ inline int pk2(float a, float b) {  // low16=bf(a), high16=bf(b)
    return __builtin_amdgcn_perm(bfr(b), bfr(a), 0x07060302);
}
static __device__ inline short8 pk8(float4 lo, float4 hi) {
    union { short8 s; int i[4]; } r;
    r.i[0] = pk2(lo.x, lo.y); r.i[1] = pk2(lo.z, lo.w);
    r.i[2] = pk2(hi.x, hi.y); r.i[3] = pk2(hi.z, hi.w);
    return r.s;
}

// ---------------------------------------------------------------------------
// Kernel 1: W_out (f32 [k][n]) -> bf16 MFMA B-fragment order (unchanged).
// ---------------------------------------------------------------------------
__global__ __launch_bounds__(256) void convert_w(const float* __restrict__ Wo,
                                                 __hip_bfloat16* __restrict__ wsw) {
    int tid = blockIdx.x * 256 + threadIdx.x;     // 0 .. 131071
    int l = tid & 63;
    int kblk = (tid >> 6) & 31;
    int ntile = tid >> 11;
    int col = ntile * 16 + (l & 15);
    int krow = kblk * 32 + (l >> 4) * 8;
#pragma unroll
    for (int j = 0; j < 8; ++j) {
        wsw[(size_t)tid * 8 + j] = __float2bfloat16(Wo[(size_t)(krow + j) * NN + col]);
    }
}

// ---------------------------------------------------------------------------
// Kernel 1b: K_state / V_state -> MFMA A-frag layouts (unchanged).
// ---------------------------------------------------------------------------
__global__ __launch_bounds__(256) void convert_kv(const float* __restrict__ Kst,
                                                  const float* __restrict__ Vst,
                                                  __hip_bfloat16* __restrict__ kfrag,
                                                  __hip_bfloat16* __restrict__ vfrag) {
    int tid = blockIdx.x * 256 + threadIdx.x;     // 0..65535
    int arr = tid >> 15;
    int idx = tid & 32767;
    int h = idx >> 11, blk = (idx >> 6) & 31, fl = idx & 63;
    int fm = fl & 15, fk = fl >> 4;
    short8 val;
    short* dst;
    if (arr == 0) {
        int mt = blk >> 1, kb = blk & 1;
        int pr = mt * 16 + fm, d0 = kb * 32 + fk * 8;
        const float* src = Kst + ((size_t)h * 256 + pr) * 64 + d0;
        float4 lo = *(const float4*)src, hi = *(const float4*)(src + 4);
        val = pack8(lo, hi);
        dst = (short*)kfrag + (size_t)idx * 8;
    } else {
        int mt = blk >> 3, kb = blk & 7;
        int d = mt * 16 + fm, pr0 = kb * 32 + fk * 8;
        const float* src = Vst + ((size_t)h * 256 + pr0) * 64 + d;
#pragma unroll
        for (int j = 0; j < 8; ++j) val[j] = f2bf(src[j * 64]);
        dst = (short*)vfrag + (size_t)idx * 8;
    }
    *(short8*)dst = val;
}

// ---------------------------------------------------------------------------
// Kernel 2 (v5): fused router + dense-MFMA SSE attention.
// Changes vs v4: gates transposed to [32][64] (8192 B, conflict-analyzed:
// reads are 2-way-broadcast = free, writes 16-consecutive = conflict-free)
// -> total LDS 41984 -> 40960 = EXACTLY 4 blocks/CU (was 3). launch_bounds
// min-waves 3 -> 4. All arithmetic bit-identical to v4.
// ---------------------------------------------------------------------------
__global__ __launch_bounds__(256, 4) void attn_v5(const float* __restrict__ x,
                                                  const float* __restrict__ Wr,
                                                  const __hip_bfloat16* __restrict__ kfrag,
                                                  const __hip_bfloat16* __restrict__ vfrag,
                                                  const int* __restrict__ kp,
                                                  __hip_bfloat16* __restrict__ hb) {
    // Aliased LDS region (40960 B total = 160KiB/4):
    //   [0,32768):  wf (heads-phase B-frags)  -- written after top-k sync
    //   [0,17408):  xs[64][68]                -- dead after logits phase
    //   [17408,26624): Lg[64][36]             -- dead after top-k phase
    //   [32768,40960): gatesT[32][64]         -- live during wf phase (disjoint)
    __shared__ __align__(16) char smem[40960];
    float (*xs)[68]     = (float (*)[68])smem;
    float (*Lg)[36]     = (float (*)[36])(smem + 17408);
    short* wf           = (short*)smem;
    float (*gatesT)[64] = (float (*)[64])(smem + 32768);

    const int lane = threadIdx.x & 63;
    const int w = threadIdx.x >> 6;
    const int l15 = lane & 15, l4 = lane >> 4;
    const int t0 = blockIdx.x * 64;
    const int h = blockIdx.y;

    // ---- stage x tile [64 t x 64 d] into LDS ----
    {
        int row = threadIdx.x >> 2, q = threadIdx.x & 3;
        const float4* src = (const float4*)(x + (size_t)(t0 + row) * DM + h * 64 + q * 16);
        float4 v0 = src[0], v1 = src[1], v2 = src[2], v3 = src[3];
        float4* dst = (float4*)&xs[row][q * 16];
        dst[0] = v0; dst[1] = v1; dst[2] = v2; dst[3] = v3;
    }

    // ---- preload router weights (exact R1 pattern) ----
    const int p = lane & 31, dh = lane >> 5;
    float wreg[32];
    {
        const float* wrp = Wr + (size_t)h * (DD * PP) + dh * 32 * PP + p;
#pragma unroll
        for (int dd = 0; dd < 32; ++dd) wreg[dd] = wrp[dd * PP];
    }
    const int kkv = kp[0];

    __syncthreads();

    // ---- scores GEMM: S^T[pr][t]; A = kfrag (global), B = x (global) ----
    short8 xb[4][2];
#pragma unroll
    for (int nt = 0; nt < 4; ++nt)
#pragma unroll
        for (int kb = 0; kb < 2; ++kb) {
            const float* bp = x + (size_t)(t0 + nt * 16 + l15) * DM + h * 64 + kb * 32 + l4 * 8;
            float4 lo = *(const float4*)bp;
            float4 hi = *(const float4*)(bp + 4);
            xb[nt][kb] = pk8(lo, hi);
        }
    short8 ka[4][2];
#pragma unroll
    for (int mi = 0; mi < 4; ++mi)
#pragma unroll
        for (int kb = 0; kb < 2; ++kb)
            ka[mi][kb] = *(const short8*)((const short*)kfrag +
                          ((size_t)(h * 32 + (w * 4 + mi) * 2 + kb) * 512 + lane * 8));

    floatx4 acc[4][4] = {};
#pragma unroll
    for (int kb = 0; kb < 2; ++kb)
#pragma unroll
        for (int mi = 0; mi < 4; ++mi)
#pragma unroll
            for (int nt = 0; nt < 4; ++nt)
                acc[mi][nt] = __builtin_amdgcn_mfma_f32_16x16x32_bf16(ka[mi][kb], xb[nt][kb], acc[mi][nt], 0, 0, 0);

    // ---- logits: arithmetic chain bitwise-identical to R1..R4 ----
    for (int it = 0; it < 16; ++it) {
        int t = w * 16 + it;
        float xf[32];
#pragma unroll
        for (int j = 0; j < 8; ++j) {
            float4 tq = *(const float4*)&xs[t][dh * 32 + 4 * j];
            xf[4 * j] = tq.x; xf[4 * j + 1] = tq.y; xf[4 * j + 2] = tq.z; xf[4 * j + 3] = tq.w;
        }
        float lg = 0.f;
#pragma unroll
        for (int dd = 0; dd < 32; ++dd) lg += xf[dd] * wreg[dd];
        lg += __shfl_xor(lg, 32);
        if (lane < 32) Lg[t][lane] = lg;
    }
    __syncthreads();

    // ---- top-k + gates, in-register per token (lanes 0..15) ----
    if (lane < 16) {
        int t = w * 16 + lane;
        float lgr[32];
        const float4* lrow = (const float4*)&Lg[t][0];
#pragma unroll
        for (int c = 0; c < 8; ++c) {
            float4 q4 = lrow[c];
            lgr[4 * c] = q4.x; lgr[4 * c + 1] = q4.y; lgr[4 * c + 2] = q4.z; lgr[4 * c + 3] = q4.w;
        }
        float a1 = -INFINITY, b2 = -INFINITY, c3 = -INFINITY, d4 = -INFINITY;
#pragma unroll
        for (int pp = 0; pp < 32; ++pp) {
            float v = lgr[pp];
            float na = fmaxf(a1, v); v = fminf(a1, v); a1 = na;
            float nb = fmaxf(b2, v); v = fminf(b2, v); b2 = nb;
            float nc = fmaxf(c3, v); v = fminf(c3, v); c3 = nc;
            d4 = fmaxf(d4, v);
        }
        float thresh = (kkv >= 4) ? d4 : (kkv == 3 ? c3 : (kkv == 2 ? b2 : a1));
        float den = 0.f;
        float garr[32];
#pragma unroll
        for (int pp = 0; pp < 32; ++pp) {
            float e = __expf(lgr[pp] - a1);
            float ge = (lgr[pp] >= thresh) ? e : 0.f;   // ref semantics: >=
            garr[pp] = ge; den += ge;
        }
        float inv = 1.f / den;
#pragma unroll
        for (int pp = 0; pp < 32; ++pp)
            gatesT[pp][t] = garr[pp] * inv;             // 16 consecutive words/instr
    }
    __syncthreads();

    // ---- r-softmax + gate -> w B-frags in LDS (overwrites dead xs/Lg) ----
#pragma unroll
    for (int mi = 0; mi < 4; ++mi) {
        const int mt = w * 4 + mi;
        const int pidx = mt * 2 + (l4 >> 1);
#pragma unroll
        for (int nt = 0; nt < 4; ++nt) {
            float g = gatesT[pidx][nt * 16 + l15];
            float s0 = acc[mi][nt][0] * 0.125f;
            float s1 = acc[mi][nt][1] * 0.125f;
            float s2 = acc[mi][nt][2] * 0.125f;
            float s3 = acc[mi][nt][3] * 0.125f;
            float mx = fmaxf(fmaxf(s0, s1), fmaxf(s2, s3));
            mx = fmaxf(mx, __shfl_xor(mx, 16));
            float e0 = __expf(s0 - mx), e1 = __expf(s1 - mx);
            float e2 = __expf(s2 - mx), e3 = __expf(s3 - mx);
            float loc = (e0 + e1) + (e2 + e3);
            float se = loc + __shfl_xor(loc, 16);
            float ws = g / se;
            int2 pk;
            pk.x = pk2(e0 * ws, e1 * ws);
            pk.y = pk2(e2 * ws, e3 * ws);
            int off = (((mt & 1) * 2 + (l4 >> 1)) * 16 + l15) * 8 + (l4 & 1) * 4;
            *(int2*)&wf[(nt * 8 + (mt >> 1)) * 512 + off] = pk;
        }
    }
    __syncthreads();

    // ---- heads GEMM: H^T[d][t] = Vfrag(A) @ wf(B) ----
    floatx4 h4[4] = {};
#pragma unroll
    for (int kb = 0; kb < 8; ++kb) {
        short8 va = *(const short8*)((const short*)vfrag +
                      ((size_t)(h * 32 + w * 8 + kb) * 512 + lane * 8));
#pragma unroll
        for (int nt = 0; nt < 4; ++nt) {
            short8 wb = *(const short8*)&wf[(nt * 8 + kb) * 512 + lane * 8];
            h4[nt] = __builtin_amdgcn_mfma_f32_16x16x32_bf16(va, wb, h4[nt], 0, 0, 0);
        }
    }
#pragma unroll
    for (int nt = 0; nt < 4; ++nt) {
        int t = t0 + nt * 16 + l15;
        int2 pk;
        pk.x = pk2(h4[nt][0], h4[nt][1]);
        pk.y = pk2(h4[nt][2], h4[nt][3]);
        *(int2*)((short*)hb + (size_t)t * DM + h * 64 + w * 16 + l4 * 4) = pk;
    }
}

// ---------------------------------------------------------------------------
// Kernel 3 (v3): 2-phase double-buffered m97-style GEMM (T3 minimum recipe)
// + bijective XCD-stripe swizzle.
//   - One barrier per K-step (was two): stage A[k+1] via global_load_lds and
//     prefetch B[k+1] into regs WHILE computing MFMAs of step k; the single
//     barrier (implicit vmcnt(0) drain) then covers both.
//   - XCD swizzle: old grid map put one N-tile column per XCD -> each XCD
//     streamed all 32 MiB of A through its 4 MiB L2 (8x32 MiB of L3/HBM
//     traffic). New map gives each XCD a contiguous 16-M-tile stripe
//     (4 MiB A + 2 MiB B working set), n fastest.
// MFMA sequence identical to v2 -> bit-identical output.
// ---------------------------------------------------------------------------
__global__ __launch_bounds__(256) void gemm_v3(const __hip_bfloat16* __restrict__ Abf,
                                               const __hip_bfloat16* __restrict__ Bsw,
                                               const float* __restrict__ bias,
                                               float* __restrict__ C) {
    __shared__ __align__(16) short As[2][4096];   // 2 x (128 rows x 32 k) = 16 KB
    const int lane = threadIdx.x & 63;
    const int wave = threadIdx.x >> 6;
    const int wm = wave >> 1, wn = wave & 1;

    // Bijective XCD-aware remap. Dispatch index = y*8 + x (x fastest),
    // hardware round-robins that index over the 8 XCDs.
    const int wg  = blockIdx.y * 8 + blockIdx.x;  // 0..1023
    const int xcd = wg & 7;
    const int loc = wg >> 3;                      // 0..127
    const int bm0 = (xcd * 16 + (loc >> 3)) * 128;  // 16 M-tiles per XCD
    const int bn0 = (loc & 7) * 128;                // n fastest within stripe

    const int l15 = lane & 15, l4 = lane >> 4;

    const short* Ap = (const short*)Abf;
    const short* Bp = (const short*)Bsw;

    // staging: chunk c (0..511): row=c>>2 of A-tile, koff=(c&3)*8.
    // wave-instr j in {0,1}: c = (wave*2+j)*64 + lane; LDS linear at c*16B.
    const int c0 = (wave * 2 + 0) * 64 + lane;
    const int c1 = (wave * 2 + 1) * 64 + lane;
    const short* g0 = Ap + (size_t)(bm0 + (c0 >> 2)) * KK + (c0 & 3) * 8;
    const short* g1 = Ap + (size_t)(bm0 + (c1 >> 2)) * KK + (c1 & 3) * 8;

    int boff[4];
#pragma unroll
    for (int nt = 0; nt < 4; ++nt)
        boff[nt] = (((bn0 >> 4) + wn * 4 + nt) * 32) * 512 + lane * 8;

    int aoff[4];
#pragma unroll
    for (int mt = 0; mt < 4; ++mt)
        aoff[mt] = ((wm * 64 + mt * 16 + l15) * 4 + l4) * 8;

    floatx4 acc[4][4] = {};

    // ---- prologue: stage k-step 0 into buf 0, prefetch B[0] ----
    __builtin_amdgcn_global_load_lds(
        (const __attribute__((address_space(1))) unsigned int*)(g0),
        (__attribute__((address_space(3))) unsigned int*)&As[0][(wave * 2 + 0) * 512], 16, 0, 0);
    __builtin_amdgcn_global_load_lds(
        (const __attribute__((address_space(1))) unsigned int*)(g1),
        (__attribute__((address_space(3))) unsigned int*)&As[0][(wave * 2 + 1) * 512], 16, 0, 0);
    short8 bcur[4], bnxt[4];
#pragma unroll
    for (int nt = 0; nt < 4; ++nt)
        bcur[nt] = *(const short8*)(Bp + boff[nt]);
    __syncthreads();                              // buf0 staged, B[0] in regs

    for (int kb = 0; kb < 32; ++kb) {
        const int cur = kb & 1;
        const int nxt = cur ^ 1;
        if (kb < 31) {
            // issue next-tile staging + B prefetch BEFORE the MFMAs (T3)
            __builtin_amdgcn_global_load_lds(
                (const __attribute__((address_space(1))) unsigned int*)(g0 + (kb + 1) * 32),
                (__attribute__((address_space(3))) unsigned int*)&As[nxt][(wave * 2 + 0) * 512], 16, 0, 0);
            __builtin_amdgcn_global_load_lds(
                (const __attribute__((address_space(1))) unsigned int*)(g1 + (kb + 1) * 32),
                (__attribute__((address_space(3))) unsigned int*)&As[nxt][(wave * 2 + 1) * 512], 16, 0, 0);
#pragma unroll
            for (int nt = 0; nt < 4; ++nt)
                bnxt[nt] = *(const short8*)(Bp + boff[nt] + (kb + 1) * 512);
        }
        short8 a[4];
#pragma unroll
        for (int mt = 0; mt < 4; ++mt)
            a[mt] = *(const short8*)&As[cur][aoff[mt]];
#pragma unroll
        for (int mt = 0; mt < 4; ++mt)
#pragma unroll
            for (int nt = 0; nt < 4; ++nt)
                acc[mt][nt] = __builtin_amdgcn_mfma_f32_16x16x32_bf16(a[mt], bcur[nt], acc[mt][nt], 0, 0, 0);
        __syncthreads();                          // drains staging + B prefetch
#pragma unroll
        for (int nt = 0; nt < 4; ++nt)
            bcur[nt] = bnxt[nt];
    }

#pragma unroll
    for (int nt = 0; nt < 4; ++nt) {
        const int col = bn0 + wn * 64 + nt * 16 + l15;
        const float bv = bias[col];
#pragma unroll
        for (int mt = 0; mt < 4; ++mt) {
            const int row0 = bm0 + wm * 64 + mt * 16 + l4 * 4;
#pragma unroll
            for (int i = 0; i < 4; ++i)
                C[(size_t)(row0 + i) * NN + col] = acc[mt][nt][i] + bv;
        }
    }
}

// ---------------------------------------------------------------------------
extern "C" void kernel_launch(void* const* d_in, const int* in_sizes, int n_in,
                              void* d_out, int out_size, void* d_ws, size_t ws_size,
                              hipStream_t stream) {
    const float* x   = (const float*)d_in[0];
    const float* Kst = (const float*)d_in[1];
    const float* Vst = (const float*)d_in[2];
    const float* Wr  = (const float*)d_in[3];
    const float* Wo  = (const float*)d_in[4];
    const float* bo  = (const float*)d_in[5];
    const int*   kp  = (const int*)d_in[6];
    float* out = (float*)d_out;

    __hip_bfloat16* hb    = (__hip_bfloat16*)d_ws;             // 16M bf16 = 32 MiB
    __hip_bfloat16* wsw   = hb + (size_t)MM * KK;              // 1M bf16  = 2 MiB
    __hip_bfloat16* kfrag = wsw + (size_t)KK * NN;             // 256K bf16
    __hip_bfloat16* vfrag = kfrag + 16 * 32 * 512;             // 256K bf16

    convert_w<<<dim3(512), 256, 0, stream>>>(Wo, wsw);
    convert_kv<<<dim3(256), 256, 0, stream>>>(Kst, Vst, kfrag, vfrag);
    attn_v5<<<dim3(NTOK / 64, HH), 256, 0, stream>>>(x, Wr, kfrag, vfrag, kp, hb);
    gemm_v3<<<dim3(NN / 128, MM / 128), 256, 0, stream>>>(hb, wsw, bo, out);
}

// Round 2
// 241.941 us; speedup vs baseline: 1.3359x; 1.3359x over previous
//
#include <hip/hip_runtime.h>
#include <hip/hip_bf16.h>

// Problem constants
#define BB 4
#define SS 4096
#define DM 1024
#define HH 16
#define PP 32
#define RR 8
#define DD 64
#define NTOK (BB*SS)          // 16384 tokens
#define MM NTOK               // GEMM M
#define NN DM                 // GEMM N
#define KK DM                 // GEMM K

typedef __attribute__((ext_vector_type(8))) short short8;
typedef __attribute__((ext_vector_type(4))) float floatx4;

static __device__ inline short f2bf(float f) {
    union { __hip_bfloat16 b; short s; } u; u.b = __float2bfloat16(f); return u.s;
}
static __device__ inline short8 pack8(float4 lo, float4 hi) {
    short8 r;
    r[0] = f2bf(lo.x); r[1] = f2bf(lo.y); r[2] = f2bf(lo.z); r[3] = f2bf(lo.w);
    r[4] = f2bf(hi.x); r[5] = f2bf(hi.y); r[6] = f2bf(hi.z); r[7] = f2bf(hi.w);
    return r;
}

// Fast RNE bf16 pack: identical bits to __float2bfloat16 for finite inputs.
static __device__ inline unsigned bfr(float f) {
    unsigned u = __float_as_uint(f);
    return u + 0x7fffu + ((u >> 16) & 1u);
}
static __device__ inline int pk2(float a, float b) {  // low16=bf(a), high16=bf(b)
    return __builtin_amdgcn_perm(bfr(b), bfr(a), 0x07060302);
}
static __device__ inline short8 pk8(float4 lo, float4 hi) {
    union { short8 s; int i[4]; } r;
    r.i[0] = pk2(lo.x, lo.y); r.i[1] = pk2(lo.z, lo.w);
    r.i[2] = pk2(hi.x, hi.y); r.i[3] = pk2(hi.z, hi.w);
    return r.s;
}

// ---------------------------------------------------------------------------
// Kernel 1: W_out (f32 [k][n]) -> bf16 MFMA B-fragment order (unchanged).
// ---------------------------------------------------------------------------
__global__ __launch_bounds__(256) void convert_w(const float* __restrict__ Wo,
                                                 __hip_bfloat16* __restrict__ wsw) {
    int tid = blockIdx.x * 256 + threadIdx.x;     // 0 .. 131071
    int l = tid & 63;
    int kblk = (tid >> 6) & 31;
    int ntile = tid >> 11;
    int col = ntile * 16 + (l & 15);
    int krow = kblk * 32 + (l >> 4) * 8;
#pragma unroll
    for (int j = 0; j < 8; ++j) {
        wsw[(size_t)tid * 8 + j] = __float2bfloat16(Wo[(size_t)(krow + j) * NN + col]);
    }
}

// ---------------------------------------------------------------------------
// Kernel 1b: K_state / V_state -> MFMA A-frag layouts (unchanged).
// ---------------------------------------------------------------------------
__global__ __launch_bounds__(256) void convert_kv(const float* __restrict__ Kst,
                                                  const float* __restrict__ Vst,
                                                  __hip_bfloat16* __restrict__ kfrag,
                                                  __hip_bfloat16* __restrict__ vfrag) {
    int tid = blockIdx.x * 256 + threadIdx.x;     // 0..65535
    int arr = tid >> 15;
    int idx = tid & 32767;
    int h = idx >> 11, blk = (idx >> 6) & 31, fl = idx & 63;
    int fm = fl & 15, fk = fl >> 4;
    short8 val;
    short* dst;
    if (arr == 0) {
        int mt = blk >> 1, kb = blk & 1;
        int pr = mt * 16 + fm, d0 = kb * 32 + fk * 8;
        const float* src = Kst + ((size_t)h * 256 + pr) * 64 + d0;
        float4 lo = *(const float4*)src, hi = *(const float4*)(src + 4);
        val = pack8(lo, hi);
        dst = (short*)kfrag + (size_t)idx * 8;
    } else {
        int mt = blk >> 3, kb = blk & 7;
        int d = mt * 16 + fm, pr0 = kb * 32 + fk * 8;
        const float* src = Vst + ((size_t)h * 256 + pr0) * 64 + d;
#pragma unroll
        for (int j = 0; j < 8; ++j) val[j] = f2bf(src[j * 64]);
        dst = (short*)vfrag + (size_t)idx * 8;
    }
    *(short8*)dst = val;
}

// ---------------------------------------------------------------------------
// Kernel 2 (v6): fused router + dense-MFMA SSE attention.
// v5 -> v6: ONLY change is __launch_bounds__(256, 4) -> (256, 3).
// The min-4 bound forced a VGPR budget the kernel can't fit (VGPR 84 -> 64,
// massive scratch spills: hbm_bytes 1.1e8 -> 4.7e8, dur 111 -> 177 us).
// At (256,3) the compiler allocates ~84 VGPR (<=128), so hardware still
// reaches 4 waves/SIMD; the 40960 B LDS (gatesT transposed) still permits
// 4 blocks/CU. Occupancy win without spills. Arithmetic bit-identical.
// ---------------------------------------------------------------------------
__global__ __launch_bounds__(256, 3) void attn_v6(const float* __restrict__ x,
                                                  const float* __restrict__ Wr,
                                                  const __hip_bfloat16* __restrict__ kfrag,
                                                  const __hip_bfloat16* __restrict__ vfrag,
                                                  const int* __restrict__ kp,
                                                  __hip_bfloat16* __restrict__ hb) {
    // Aliased LDS region (40960 B total = 160KiB/4):
    //   [0,32768):  wf (heads-phase B-frags)  -- written after top-k sync
    //   [0,17408):  xs[64][68]                -- dead after logits phase
    //   [17408,26624): Lg[64][36]             -- dead after top-k phase
    //   [32768,40960): gatesT[32][64]         -- live during wf phase (disjoint)
    __shared__ __align__(16) char smem[40960];
    float (*xs)[68]     = (float (*)[68])smem;
    float (*Lg)[36]     = (float (*)[36])(smem + 17408);
    short* wf           = (short*)smem;
    float (*gatesT)[64] = (float (*)[64])(smem + 32768);

    const int lane = threadIdx.x & 63;
    const int w = threadIdx.x >> 6;
    const int l15 = lane & 15, l4 = lane >> 4;
    const int t0 = blockIdx.x * 64;
    const int h = blockIdx.y;

    // ---- stage x tile [64 t x 64 d] into LDS ----
    {
        int row = threadIdx.x >> 2, q = threadIdx.x & 3;
        const float4* src = (const float4*)(x + (size_t)(t0 + row) * DM + h * 64 + q * 16);
        float4 v0 = src[0], v1 = src[1], v2 = src[2], v3 = src[3];
        float4* dst = (float4*)&xs[row][q * 16];
        dst[0] = v0; dst[1] = v1; dst[2] = v2; dst[3] = v3;
    }

    // ---- preload router weights (exact R1 pattern) ----
    const int p = lane & 31, dh = lane >> 5;
    float wreg[32];
    {
        const float* wrp = Wr + (size_t)h * (DD * PP) + dh * 32 * PP + p;
#pragma unroll
        for (int dd = 0; dd < 32; ++dd) wreg[dd] = wrp[dd * PP];
    }
    const int kkv = kp[0];

    __syncthreads();

    // ---- scores GEMM: S^T[pr][t]; A = kfrag (global), B = x (global) ----
    short8 xb[4][2];
#pragma unroll
    for (int nt = 0; nt < 4; ++nt)
#pragma unroll
        for (int kb = 0; kb < 2; ++kb) {
            const float* bp = x + (size_t)(t0 + nt * 16 + l15) * DM + h * 64 + kb * 32 + l4 * 8;
            float4 lo = *(const float4*)bp;
            float4 hi = *(const float4*)(bp + 4);
            xb[nt][kb] = pk8(lo, hi);
        }
    short8 ka[4][2];
#pragma unroll
    for (int mi = 0; mi < 4; ++mi)
#pragma unroll
        for (int kb = 0; kb < 2; ++kb)
            ka[mi][kb] = *(const short8*)((const short*)kfrag +
                          ((size_t)(h * 32 + (w * 4 + mi) * 2 + kb) * 512 + lane * 8));

    floatx4 acc[4][4] = {};
#pragma unroll
    for (int kb = 0; kb < 2; ++kb)
#pragma unroll
        for (int mi = 0; mi < 4; ++mi)
#pragma unroll
            for (int nt = 0; nt < 4; ++nt)
                acc[mi][nt] = __builtin_amdgcn_mfma_f32_16x16x32_bf16(ka[mi][kb], xb[nt][kb], acc[mi][nt], 0, 0, 0);

    // ---- logits: arithmetic chain bitwise-identical to R1..R5 ----
    for (int it = 0; it < 16; ++it) {
        int t = w * 16 + it;
        float xf[32];
#pragma unroll
        for (int j = 0; j < 8; ++j) {
            float4 tq = *(const float4*)&xs[t][dh * 32 + 4 * j];
            xf[4 * j] = tq.x; xf[4 * j + 1] = tq.y; xf[4 * j + 2] = tq.z; xf[4 * j + 3] = tq.w;
        }
        float lg = 0.f;
#pragma unroll
        for (int dd = 0; dd < 32; ++dd) lg += xf[dd] * wreg[dd];
        lg += __shfl_xor(lg, 32);
        if (lane < 32) Lg[t][lane] = lg;
    }
    __syncthreads();

    // ---- top-k + gates, in-register per token (lanes 0..15) ----
    if (lane < 16) {
        int t = w * 16 + lane;
        float lgr[32];
        const float4* lrow = (const float4*)&Lg[t][0];
#pragma unroll
        for (int c = 0; c < 8; ++c) {
            float4 q4 = lrow[c];
            lgr[4 * c] = q4.x; lgr[4 * c + 1] = q4.y; lgr[4 * c + 2] = q4.z; lgr[4 * c + 3] = q4.w;
        }
        float a1 = -INFINITY, b2 = -INFINITY, c3 = -INFINITY, d4 = -INFINITY;
#pragma unroll
        for (int pp = 0; pp < 32; ++pp) {
            float v = lgr[pp];
            float na = fmaxf(a1, v); v = fminf(a1, v); a1 = na;
            float nb = fmaxf(b2, v); v = fminf(b2, v); b2 = nb;
            float nc = fmaxf(c3, v); v = fminf(c3, v); c3 = nc;
            d4 = fmaxf(d4, v);
        }
        float thresh = (kkv >= 4) ? d4 : (kkv == 3 ? c3 : (kkv == 2 ? b2 : a1));
        float den = 0.f;
        float garr[32];
#pragma unroll
        for (int pp = 0; pp < 32; ++pp) {
            float e = __expf(lgr[pp] - a1);
            float ge = (lgr[pp] >= thresh) ? e : 0.f;   // ref semantics: >=
            garr[pp] = ge; den += ge;
        }
        float inv = 1.f / den;
#pragma unroll
        for (int pp = 0; pp < 32; ++pp)
            gatesT[pp][t] = garr[pp] * inv;             // 16 consecutive words/instr
    }
    __syncthreads();

    // ---- r-softmax + gate -> w B-frags in LDS (overwrites dead xs/Lg) ----
#pragma unroll
    for (int mi = 0; mi < 4; ++mi) {
        const int mt = w * 4 + mi;
        const int pidx = mt * 2 + (l4 >> 1);
#pragma unroll
        for (int nt = 0; nt < 4; ++nt) {
            float g = gatesT[pidx][nt * 16 + l15];
            float s0 = acc[mi][nt][0] * 0.125f;
            float s1 = acc[mi][nt][1] * 0.125f;
            float s2 = acc[mi][nt][2] * 0.125f;
            float s3 = acc[mi][nt][3] * 0.125f;
            float mx = fmaxf(fmaxf(s0, s1), fmaxf(s2, s3));
            mx = fmaxf(mx, __shfl_xor(mx, 16));
            float e0 = __expf(s0 - mx), e1 = __expf(s1 - mx);
            float e2 = __expf(s2 - mx), e3 = __expf(s3 - mx);
            float loc = (e0 + e1) + (e2 + e3);
            float se = loc + __shfl_xor(loc, 16);
            float ws = g / se;
            int2 pk;
            pk.x = pk2(e0 * ws, e1 * ws);
            pk.y = pk2(e2 * ws, e3 * ws);
            int off = (((mt & 1) * 2 + (l4 >> 1)) * 16 + l15) * 8 + (l4 & 1) * 4;
            *(int2*)&wf[(nt * 8 + (mt >> 1)) * 512 + off] = pk;
        }
    }
    __syncthreads();

    // ---- heads GEMM: H^T[d][t] = Vfrag(A) @ wf(B) ----
    floatx4 h4[4] = {};
#pragma unroll
    for (int kb = 0; kb < 8; ++kb) {
        short8 va = *(const short8*)((const short*)vfrag +
                      ((size_t)(h * 32 + w * 8 + kb) * 512 + lane * 8));
#pragma unroll
        for (int nt = 0; nt < 4; ++nt) {
            short8 wb = *(const short8*)&wf[(nt * 8 + kb) * 512 + lane * 8];
            h4[nt] = __builtin_amdgcn_mfma_f32_16x16x32_bf16(va, wb, h4[nt], 0, 0, 0);
        }
    }
#pragma unroll
    for (int nt = 0; nt < 4; ++nt) {
        int t = t0 + nt * 16 + l15;
        int2 pk;
        pk.x = pk2(h4[nt][0], h4[nt][1]);
        pk.y = pk2(h4[nt][2], h4[nt][3]);
        *(int2*)((short*)hb + (size_t)t * DM + h * 64 + w * 16 + l4 * 4) = pk;
    }
}

// ---------------------------------------------------------------------------
// Kernel 3 (v3): 2-phase double-buffered m97-style GEMM (T3 minimum recipe)
// + bijective XCD-stripe swizzle. Unchanged from round 1.
// ---------------------------------------------------------------------------
__global__ __launch_bounds__(256) void gemm_v3(const __hip_bfloat16* __restrict__ Abf,
                                               const __hip_bfloat16* __restrict__ Bsw,
                                               const float* __restrict__ bias,
                                               float* __restrict__ C) {
    __shared__ __align__(16) short As[2][4096];   // 2 x (128 rows x 32 k) = 16 KB
    const int lane = threadIdx.x & 63;
    const int wave = threadIdx.x >> 6;
    const int wm = wave >> 1, wn = wave & 1;

    // Bijective XCD-aware remap. Dispatch index = y*8 + x (x fastest),
    // hardware round-robins that index over the 8 XCDs.
    const int wg  = blockIdx.y * 8 + blockIdx.x;  // 0..1023
    const int xcd = wg & 7;
    const int loc = wg >> 3;                      // 0..127
    const int bm0 = (xcd * 16 + (loc >> 3)) * 128;  // 16 M-tiles per XCD
    const int bn0 = (loc & 7) * 128;                // n fastest within stripe

    const int l15 = lane & 15, l4 = lane >> 4;

    const short* Ap = (const short*)Abf;
    const short* Bp = (const short*)Bsw;

    // staging: chunk c (0..511): row=c>>2 of A-tile, koff=(c&3)*8.
    // wave-instr j in {0,1}: c = (wave*2+j)*64 + lane; LDS linear at c*16B.
    const int c0 = (wave * 2 + 0) * 64 + lane;
    const int c1 = (wave * 2 + 1) * 64 + lane;
    const short* g0 = Ap + (size_t)(bm0 + (c0 >> 2)) * KK + (c0 & 3) * 8;
    const short* g1 = Ap + (size_t)(bm0 + (c1 >> 2)) * KK + (c1 & 3) * 8;

    int boff[4];
#pragma unroll
    for (int nt = 0; nt < 4; ++nt)
        boff[nt] = (((bn0 >> 4) + wn * 4 + nt) * 32) * 512 + lane * 8;

    int aoff[4];
#pragma unroll
    for (int mt = 0; mt < 4; ++mt)
        aoff[mt] = ((wm * 64 + mt * 16 + l15) * 4 + l4) * 8;

    floatx4 acc[4][4] = {};

    // ---- prologue: stage k-step 0 into buf 0, prefetch B[0] ----
    __builtin_amdgcn_global_load_lds(
        (const __attribute__((address_space(1))) unsigned int*)(g0),
        (__attribute__((address_space(3))) unsigned int*)&As[0][(wave * 2 + 0) * 512], 16, 0, 0);
    __builtin_amdgcn_global_load_lds(
        (const __attribute__((address_space(1))) unsigned int*)(g1),
        (__attribute__((address_space(3))) unsigned int*)&As[0][(wave * 2 + 1) * 512], 16, 0, 0);
    short8 bcur[4], bnxt[4];
#pragma unroll
    for (int nt = 0; nt < 4; ++nt)
        bcur[nt] = *(const short8*)(Bp + boff[nt]);
    __syncthreads();                              // buf0 staged, B[0] in regs

    for (int kb = 0; kb < 32; ++kb) {
        const int cur = kb & 1;
        const int nxt = cur ^ 1;
        if (kb < 31) {
            // issue next-tile staging + B prefetch BEFORE the MFMAs (T3)
            __builtin_amdgcn_global_load_lds(
                (const __attribute__((address_space(1))) unsigned int*)(g0 + (kb + 1) * 32),
                (__attribute__((address_space(3))) unsigned int*)&As[nxt][(wave * 2 + 0) * 512], 16, 0, 0);
            __builtin_amdgcn_global_load_lds(
                (const __attribute__((address_space(1))) unsigned int*)(g1 + (kb + 1) * 32),
                (__attribute__((address_space(3))) unsigned int*)&As[nxt][(wave * 2 + 1) * 512], 16, 0, 0);
#pragma unroll
            for (int nt = 0; nt < 4; ++nt)
                bnxt[nt] = *(const short8*)(Bp + boff[nt] + (kb + 1) * 512);
        }
        short8 a[4];
#pragma unroll
        for (int mt = 0; mt < 4; ++mt)
            a[mt] = *(const short8*)&As[cur][aoff[mt]];
#pragma unroll
        for (int mt = 0; mt < 4; ++mt)
#pragma unroll
            for (int nt = 0; nt < 4; ++nt)
                acc[mt][nt] = __builtin_amdgcn_mfma_f32_16x16x32_bf16(a[mt], bcur[nt], acc[mt][nt], 0, 0, 0);
        __syncthreads();                          // drains staging + B prefetch
#pragma unroll
        for (int nt = 0; nt < 4; ++nt)
            bcur[nt] = bnxt[nt];
    }

#pragma unroll
    for (int nt = 0; nt < 4; ++nt) {
        const int col = bn0 + wn * 64 + nt * 16 + l15;
        const float bv = bias[col];
#pragma unroll
        for (int mt = 0; mt < 4; ++mt) {
            const int row0 = bm0 + wm * 64 + mt * 16 + l4 * 4;
#pragma unroll
            for (int i = 0; i < 4; ++i)
                C[(size_t)(row0 + i) * NN + col] = acc[mt][nt][i] + bv;
        }
    }
}

// ---------------------------------------------------------------------------
extern "C" void kernel_launch(void* const* d_in, const int* in_sizes, int n_in,
                              void* d_out, int out_size, void* d_ws, size_t ws_size,
                              hipStream_t stream) {
    const float* x   = (const float*)d_in[0];
    const float* Kst = (const float*)d_in[1];
    const float* Vst = (const float*)d_in[2];
    const float* Wr  = (const float*)d_in[3];
    const float* Wo  = (const float*)d_in[4];
    const float* bo  = (const float*)d_in[5];
    const int*   kp  = (const int*)d_in[6];
    float* out = (float*)d_out;

    __hip_bfloat16* hb    = (__hip_bfloat16*)d_ws;             // 16M bf16 = 32 MiB
    __hip_bfloat16* wsw   = hb + (size_t)MM * KK;              // 1M bf16  = 2 MiB
    __hip_bfloat16* kfrag = wsw + (size_t)KK * NN;             // 256K bf16
    __hip_bfloat16* vfrag = kfrag + 16 * 32 * 512;             // 256K bf16

    convert_w<<<dim3(512), 256, 0, stream>>>(Wo, wsw);
    convert_kv<<<dim3(256), 256, 0, stream>>>(Kst, Vst, kfrag, vfrag);
    attn_v6<<<dim3(NTOK / 64, HH), 256, 0, stream>>>(x, Wr, kfrag, vfrag, kp, hb);
    gemm_v3<<<dim3(NN / 128, MM / 128), 256, 0, stream>>>(hb, wsw, bo, out);
}